// Round 5
// baseline (168.136 us; speedup 1.0000x reference)
//
#include <hip/hip_runtime.h>

typedef short short8 __attribute__((ext_vector_type(8)));
typedef float f32x4 __attribute__((ext_vector_type(4)));
typedef unsigned int uint4v __attribute__((ext_vector_type(4)));

#define H_ 384
#define W_ 384
#define C_ 32
#define HW_ 147456          // H_*W_
#define HP1F 385.0f         // (H+2*pad)-1 as float
#define NB 2                // pixel batches per wave

__device__ __forceinline__ unsigned short f2bf(float f) {
  unsigned int u = __float_as_uint(f);
  u += 0x7fffu + ((u >> 16) & 1u);   // RNE
  return (unsigned short)(u >> 16);
}

__device__ __forceinline__ unsigned pack2(float a, float b) {
  return (unsigned)f2bf(a) | ((unsigned)f2bf(b) << 16);
}

// Issue one tap for both phases: compute branch + weights (fast/general
// formulas verbatim from R4 -> bit-exact) and put the 8 corner gathers in
// flight. Outputs: 8 weights + 8 corner vectors (named regs at call sites).
__device__ __forceinline__ void issue_tap(
    const float* __restrict__ x, float2 oA, float2 oB,
    int i, int di, int jA, int jB, int dj, int b, int c0,
    float& wA00, float& wA01, float& wA10, float& wA11,
    float& wB00, float& wB01, float& wB10, float& wB11,
    f32x4& cA00, f32x4& cA01, f32x4& cA10, f32x4& cA11,
    f32x4& cB00, f32x4& cB01, f32x4& cB10, f32x4& cB11) {
  float yfA = (float)(i + di) + oA.y;
  float xfA = (float)(jA + dj) + oA.x;
  yfA = fminf(fmaxf(yfA, 0.f), HP1F);
  xfA = fminf(fmaxf(xfA, 0.f), HP1F);
  const float y0fA = floorf(yfA), x0fA = floorf(xfA);
  const int y0A = (int)y0fA, x0A = (int)x0fA;

  float yfB = (float)(i + di) + oB.y;
  float xfB = (float)(jB + dj) + oB.x;
  yfB = fminf(fmaxf(yfB, 0.f), HP1F);
  xfB = fminf(fmaxf(xfB, 0.f), HP1F);
  const float y0fB = floorf(yfB), x0fB = floorf(xfB);
  const int y0B = (int)y0fB, x0B = (int)x0fB;

  const int fastA = ((unsigned)(y0A - 1) < 383u) & ((unsigned)(x0A - 1) < 383u);
  const int fastB = ((unsigned)(y0B - 1) < 383u) & ((unsigned)(x0B - 1) < 383u);

  if (__all(fastA & fastB)) {
    const float wy1A = yfA - y0fA, wy0A = (y0fA + 1.0f) - yfA;
    const float wx1A = xfA - x0fA, wx0A = (x0fA + 1.0f) - xfA;
    wA00 = wy0A * wx0A; wA01 = wy0A * wx1A;
    wA10 = wy1A * wx0A; wA11 = wy1A * wx1A;
    const float wy1B = yfB - y0fB, wy0B = (y0fB + 1.0f) - yfB;
    const float wx1B = xfB - x0fB, wx0B = (x0fB + 1.0f) - xfB;
    wB00 = wy0B * wx0B; wB01 = wy0B * wx1B;
    wB10 = wy1B * wx0B; wB11 = wy1B * wx1B;

    const int baseA = ((b * H_ + (y0A - 1)) * W_ + (x0A - 1)) * C_ + c0;
    const int baseB = ((b * H_ + (y0B - 1)) * W_ + (x0B - 1)) * C_ + c0;
    // 8 unconditional independent 16B gathers, 8-lane-contiguous each
    cA00 = *(const f32x4*)(x + baseA);
    cA01 = *(const f32x4*)(x + baseA + C_);
    cA10 = *(const f32x4*)(x + baseA + W_ * C_);
    cA11 = *(const f32x4*)(x + baseA + W_ * C_ + C_);
    cB00 = *(const f32x4*)(x + baseB);
    cB01 = *(const f32x4*)(x + baseB + C_);
    cB10 = *(const f32x4*)(x + baseB + W_ * C_);
    cB11 = *(const f32x4*)(x + baseB + W_ * C_ + C_);
  } else {
    // general path: verbatim R0/R4 slow-path arithmetic (guarded loads,
    // pad corners -> 0); weights use the clamped y1/x1 formulas.
    const f32x4 z = {0.f, 0.f, 0.f, 0.f};
    {
      const int y1 = min(y0A + 1, 385);
      const int x1 = min(x0A + 1, 385);
      const float wy1 = yfA - y0fA, wy0 = (float)y1 - yfA;
      const float wx1 = xfA - x0fA, wx0 = (float)x1 - xfA;
      wA00 = wy0 * wx0; wA01 = wy0 * wx1;
      wA10 = wy1 * wx0; wA11 = wy1 * wx1;
      const int yu0 = y0A - 1, xu0 = x0A - 1;
      const bool vy0 = (unsigned)yu0 < 384u, vy1 = (unsigned)(y1 - 1) < 384u;
      const bool vx0 = (unsigned)xu0 < 384u, vx1 = (unsigned)(x1 - 1) < 384u;
      const int base00 = ((b * H_ + yu0) * W_ + xu0) * C_ + c0;
      const int ddx = (x1 - x0A) * C_;
      const int ddy = (y1 - y0A) * (W_ * C_);
      cA00 = z; cA01 = z; cA10 = z; cA11 = z;
      if (vy0 && vx0) cA00 = *(const f32x4*)(x + base00);
      if (vy0 && vx1) cA01 = *(const f32x4*)(x + base00 + ddx);
      if (vy1 && vx0) cA10 = *(const f32x4*)(x + base00 + ddy);
      if (vy1 && vx1) cA11 = *(const f32x4*)(x + base00 + ddy + ddx);
    }
    {
      const int y1 = min(y0B + 1, 385);
      const int x1 = min(x0B + 1, 385);
      const float wy1 = yfB - y0fB, wy0 = (float)y1 - yfB;
      const float wx1 = xfB - x0fB, wx0 = (float)x1 - xfB;
      wB00 = wy0 * wx0; wB01 = wy0 * wx1;
      wB10 = wy1 * wx0; wB11 = wy1 * wx1;
      const int yu0 = y0B - 1, xu0 = x0B - 1;
      const bool vy0 = (unsigned)yu0 < 384u, vy1 = (unsigned)(y1 - 1) < 384u;
      const bool vx0 = (unsigned)xu0 < 384u, vx1 = (unsigned)(x1 - 1) < 384u;
      const int base00 = ((b * H_ + yu0) * W_ + xu0) * C_ + c0;
      const int ddx = (x1 - x0B) * C_;
      const int ddy = (y1 - y0B) * (W_ * C_);
      cB00 = z; cB01 = z; cB10 = z; cB11 = z;
      if (vy0 && vx0) cB00 = *(const f32x4*)(x + base00);
      if (vy0 && vx1) cB01 = *(const f32x4*)(x + base00 + ddx);
      if (vy1 && vx0) cB10 = *(const f32x4*)(x + base00 + ddy);
      if (vy1 && vx1) cB11 = *(const f32x4*)(x + base00 + ddy + ddx);
    }
  }
}

__global__ __launch_bounds__(256) void deform_conv_kernel(
    const float* __restrict__ x, const float* __restrict__ off,
    const float* __restrict__ kern, const float* __restrict__ bias,
    float* __restrict__ out) {
  // R5: depth-2 software pipeline over the tap loop. Per iteration:
  //   1. interp tap kk (consumes its 8 corner regs -> dead)
  //   2. branch+weights+ISSUE the 8 gathers of tap kk+1 (fresh named regs)
  //   3. pack/bpermute/ds_read/MFMA of tap kk  <- kk+1 latency hides here
  // R4 exposed ~200cy of L2 latency per tap because each tap's guarded
  // loads couldn't be hoisted above the previous tap's branch join.
  // Named regs only (no arrays -> no scratch, R2 lesson); peak corner
  // pressure stays 8 x f32x4 due to interp-before-issue ordering.
  __shared__ short ldsB[9216];

  const int tid = threadIdx.x;
  const int lane = tid & 63;

  // ---- stage packed B fragments (bf16, MFMA B-operand layout) into LDS ----
  {
    unsigned short* pk = (unsigned short*)ldsB;
    for (int e = tid; e < 1152; e += 256) {   // 2 f-tiles * 9 k-steps * 64 lanes
      const int ln = e & 63;
      const int kk = (e >> 6) % 9;
      const int nt = e / 576;
      const int f = nt * 16 + (ln & 15);
      const int q2 = ln >> 4;
      unsigned short rr[8];
#pragma unroll
      for (int i2 = 0; i2 < 8; ++i2) {
        const int c = q2 * 8 + i2;                     // contraction idx = kk*32 + c
        rr[i2] = f2bf(kern[(kk * 32 + c) * 32 + f]);
      }
      uint4 w;
      w.x = rr[0] | ((unsigned)rr[1] << 16);
      w.y = rr[2] | ((unsigned)rr[3] << 16);
      w.z = rr[4] | ((unsigned)rr[5] << 16);
      w.w = rr[6] | ((unsigned)rr[7] << 16);
      *(uint4*)&pk[e * 8] = w;
    }
    __syncthreads();   // only barrier in the kernel; LDS is read-only after
  }
  const short8* bp = (const short8*)ldsB;

  const float bias0 = bias[lane & 15];
  const float bias1 = bias[16 + (lane & 15)];

  // gather-lane mapping: 8 lanes cover one pixel-corner row (coalesced)
  const int q  = lane >> 3;         // pixel slot within 8
  const int cq = lane & 7;          // channel quad
  const int c0 = cq * 4;

  // MFMA-lane mapping (destination of the bpermute redistribution)
  const int mrow = lane & 15;       // A row = pixel within 16-group
  const int qq = lane >> 4;         // A K-slice: channels qq*8..+7
  const int sl0 = (((mrow & 7) << 3) + (qq << 1)) << 2;
  const int sl1 = sl0 + 4;
  const bool hi = (mrow & 8) != 0;  // pixels 8..15 come from phase B

  // XCD-aware swizzle: bijection over [0,2304): blk=8r+q -> 288r+q, so each
  // XCD gets 96 contiguous image rows and fetches its halo exactly once.
  const int lb = (blockIdx.x & 7) * 288 + (blockIdx.x >> 3);

  for (int nb = 0; nb < NB; ++nb) {
    const int g = lb * (4 * NB) + nb * 4 + (tid >> 6);   // wave-group index
    const int P0 = g << 4;                               // first of 16 pixels
    const int b = (P0 >= HW_) ? 1 : 0;
    const int rem = P0 - b * HW_;
    const int i = rem / W_;
    const int j0 = rem - i * W_;     // group never crosses a row (W%16==0)
    const int jA = j0 + q;           // phase-A pixel (m = q)
    const int jB = j0 + 8 + q;       // phase-B pixel (m = 8+q)

    const float* opixA = off + (size_t)(i * W_ + jA) * 18;
    const float* opixB = off + (size_t)(i * W_ + jB) * 18;

    f32x4 acc0 = {bias0, bias0, bias0, bias0};
    f32x4 acc1 = {bias1, bias1, bias1, bias1};

    // pipeline state: weights + in-flight corners for the CURRENT tap
    float wA00, wA01, wA10, wA11, wB00, wB01, wB10, wB11;
    f32x4 cA00, cA01, cA10, cA11, cB00, cB01, cB10, cB11;
    // NEXT-tap set
    float nA00, nA01, nA10, nA11, nB00, nB01, nB10, nB11;
    f32x4 dA00, dA01, dA10, dA11, dB00, dB01, dB10, dB11;

    // prologue: tap 0 issued; offsets for tap 1 prefetched
    float2 oA = *(const float2*)(opixA);
    float2 oB = *(const float2*)(opixB);
    issue_tap(x, oA, oB, i, 0, jA, jB, 0, b, c0,
              wA00, wA01, wA10, wA11, wB00, wB01, wB10, wB11,
              cA00, cA01, cA10, cA11, cB00, cB01, cB10, cB11);
    float2 oA1 = *(const float2*)(opixA + 2);
    float2 oB1 = *(const float2*)(opixB + 2);

#pragma unroll
    for (int kk = 0; kk < 9; ++kk) {
      // 1. interp current tap (vmcnt waits happen here, in arrival order)
      const f32x4 vA = wA00 * cA00 + wA01 * cA01 + wA10 * cA10 + wA11 * cA11;
      const f32x4 vB = wB00 * cB00 + wB01 * cB01 + wB10 * cB10 + wB11 * cB11;

      // 2. issue next tap's gathers (latency hides under step 3)
      if (kk < 8) {
        const int di1 = (kk + 1) / 3;
        const int dj1 = (kk + 1) - di1 * 3;
        issue_tap(x, oA1, oB1, i, di1, jA, jB, dj1, b, c0,
                  nA00, nA01, nA10, nA11, nB00, nB01, nB10, nB11,
                  dA00, dA01, dA10, dA11, dB00, dB01, dB10, dB11);
      }
      if (kk < 7) {
        oA1 = *(const float2*)(opixA + (kk + 2) * 2);
        oB1 = *(const float2*)(opixB + (kk + 2) * 2);
      }

      // 3. pack -> bpermute crossbar -> MFMA (tail work covering kk+1 loads)
      const int a0 = (int)pack2(vA[0], vA[1]);
      const int a1 = (int)pack2(vA[2], vA[3]);
      const int b0 = (int)pack2(vB[0], vB[1]);
      const int b1 = (int)pack2(vB[2], vB[3]);

      const int pa0 = __builtin_amdgcn_ds_bpermute(sl0, a0);
      const int pb0 = __builtin_amdgcn_ds_bpermute(sl0, b0);
      const int pa1 = __builtin_amdgcn_ds_bpermute(sl0, a1);
      const int pb1 = __builtin_amdgcn_ds_bpermute(sl0, b1);
      const int pa2 = __builtin_amdgcn_ds_bpermute(sl1, a0);
      const int pb2 = __builtin_amdgcn_ds_bpermute(sl1, b0);
      const int pa3 = __builtin_amdgcn_ds_bpermute(sl1, a1);
      const int pb3 = __builtin_amdgcn_ds_bpermute(sl1, b1);
      const uint4v uu = {(unsigned)(hi ? pb0 : pa0), (unsigned)(hi ? pb1 : pa1),
                         (unsigned)(hi ? pb2 : pa2), (unsigned)(hi ? pb3 : pa3)};
      const short8 af = __builtin_bit_cast(short8, uu);

      acc0 = __builtin_amdgcn_mfma_f32_16x16x32_bf16(af, bp[kk * 64 + lane], acc0, 0, 0, 0);
      acc1 = __builtin_amdgcn_mfma_f32_16x16x32_bf16(af, bp[(9 + kk) * 64 + lane], acc1, 0, 0, 0);

      // 4. rotate pipeline state (SSA renames after full unroll)
      if (kk < 8) {
        wA00 = nA00; wA01 = nA01; wA10 = nA10; wA11 = nA11;
        wB00 = nB00; wB01 = nB01; wB10 = nB10; wB11 = nB11;
        cA00 = dA00; cA01 = dA01; cA10 = dA10; cA11 = dA11;
        cB00 = dB00; cB01 = dB01; cB10 = dB10; cB11 = dB11;
      }
    }

    // D layout: col = lane&15, row = qq*4 + reg
    float* op = out + (size_t)(P0 + qq * 4) * 32 + (lane & 15);
#pragma unroll
    for (int r = 0; r < 4; ++r) {
      op[r * 32] = acc0[r];
      op[r * 32 + 16] = acc1[r];
    }
  }
}

extern "C" void kernel_launch(void* const* d_in, const int* in_sizes, int n_in,
                              void* d_out, int out_size, void* d_ws, size_t ws_size,
                              hipStream_t stream) {
  const float* x    = (const float*)d_in[0];
  const float* off  = (const float*)d_in[1];
  const float* kern = (const float*)d_in[2];
  const float* bias = (const float*)d_in[3];
  float* out = (float*)d_out;
  // 294912 pixels / (4 waves * 16 px * NB batches) = 2304 blocks
  deform_conv_kernel<<<dim3(2304), dim3(256), 0, stream>>>(x, off, kern, bias, out);
}